// Round 1
// baseline (441.340 us; speedup 1.0000x reference)
//
#include <hip/hip_runtime.h>

#define S_DIM 1024
#define D_DIM 64
#define H_DIM 8
#define TQ 16

typedef __attribute__((ext_vector_type(4))) float f32x4;
typedef __attribute__((ext_vector_type(4))) int i32x4;
typedef __attribute__((ext_vector_type(4))) unsigned short u16x4;
typedef __attribute__((ext_vector_type(8))) short short8;

__device__ inline unsigned short f2bf(float x) {
  // round-to-nearest-even fp32 -> bf16
  unsigned int u = __builtin_bit_cast(unsigned int, x);
  u += 0x7fffu + ((u >> 16) & 1u);
  return (unsigned short)(u >> 16);
}

__device__ inline short8 pack8(f32x4 a, f32x4 b) {
  short8 r;
  r[0] = (short)f2bf(a.x); r[1] = (short)f2bf(a.y);
  r[2] = (short)f2bf(a.z); r[3] = (short)f2bf(a.w);
  r[4] = (short)f2bf(b.x); r[5] = (short)f2bf(b.y);
  r[6] = (short)f2bf(b.z); r[7] = (short)f2bf(b.w);
  return r;
}

__global__ __launch_bounds__(256)
void sdpa_kernel(const float* __restrict__ qp, const float* __restrict__ kp,
                 const float* __restrict__ vp, const float* __restrict__ sphp,
                 const int* __restrict__ maskp,
                 float* __restrict__ outp, float* __restrict__ pp)
{
  // stride pads chosen for ~2-way-or-better LDS bank behavior:
  // sc: 1028 floats  (==4 mod 32 words), pb: 1032 shorts (2064B, 16B-aligned rows)
  // vt: 136 shorts   (272B rows, 16B-aligned)
  __shared__ float          sc[TQ][1028];   // raw scores (fp32)       65792 B
  __shared__ unsigned short pb[TQ][1032];   // p_attn (bf16) for PV    33024 B
  __shared__ unsigned short vt[64][136];    // V^T chunk (bf16)        17408 B

  const int tid   = threadIdx.x;
  const int lane  = tid & 63;
  const int wave  = tid >> 6;
  const int row16 = lane & 15;   // MFMA: A.m / B.n / C.col index
  const int quad  = lane >> 4;   // MFMA: k-quad / C.row-quad

  const int bh = blockIdx.x >> 6;        // 32 (b,h) pairs
  const int qt = blockIdx.x & 63;        // 64 q-tiles of 16 rows
  const int b  = bh >> 3;                // H=8
  const int q0 = qt * TQ;

  const size_t bhS = (size_t)bh * S_DIM;

  // ---------- Phase 1: raw scores S = (Q/8) K^T via MFMA ----------
  // A-frag (Q): lane holds Q[q0+row16][kk*32 + quad*8 + j], j=0..7 — 8 contiguous fp32
  const float* qrow = qp + (bhS + q0 + row16) * D_DIM + quad * 8;
  const f32x4 s8 = {0.125f, 0.125f, 0.125f, 0.125f};  // 1/TEMPERATURE
  f32x4 qa = *(const f32x4*)(qrow);
  f32x4 qb = *(const f32x4*)(qrow + 4);
  f32x4 qc = *(const f32x4*)(qrow + 32);
  f32x4 qd = *(const f32x4*)(qrow + 36);
  const short8 aq0 = pack8(qa * s8, qb * s8);
  const short8 aq1 = pack8(qc * s8, qd * s8);

  #pragma unroll 4
  for (int t = 0; t < 16; ++t) {
    const int k0 = t * 64 + wave * 16;   // wave-private 16-col k tile
    // B-frag (K^T): lane holds K[k0+row16][kk*32 + quad*8 + j] — contiguous
    const float* krow = kp + (bhS + k0 + row16) * D_DIM + quad * 8;
    f32x4 ka = *(const f32x4*)(krow);
    f32x4 kb = *(const f32x4*)(krow + 4);
    f32x4 kc = *(const f32x4*)(krow + 32);
    f32x4 kd = *(const f32x4*)(krow + 36);
    f32x4 acc = {0.f, 0.f, 0.f, 0.f};
    acc = __builtin_amdgcn_mfma_f32_16x16x32_bf16(aq0, pack8(ka, kb), acc, 0, 0, 0);
    acc = __builtin_amdgcn_mfma_f32_16x16x32_bf16(aq1, pack8(kc, kd), acc, 0, 0, 0);
    // C layout: col = row16 (k), row = quad*4+r (q local)
    const int kg = k0 + row16;
    #pragma unroll
    for (int r = 0; r < 4; ++r)
      sc[quad * 4 + r][kg] = acc[r];
  }
  __syncthreads();

  // ---------- Phase 2: sph*mask, softmax; write p (fp32 global) + pb (bf16 LDS) ----------
  for (int r = wave; r < TQ; r += 4) {          // wave owns whole rows
    const float* sprow = sphp + (bhS + q0 + r) * S_DIM;
    const int*   mrow  = maskp + ((size_t)b * S_DIM + q0 + r) * S_DIM;
    float*       prow  = pp + (bhS + q0 + r) * S_DIM;
    f32x4 vals[4];
    float mx = -3.0e38f;
    #pragma unroll
    for (int it = 0; it < 4; ++it) {
      const int j = lane * 4 + it * 256;        // coalesced f32x4 streams
      f32x4 s4 = *(const f32x4*)&sc[r][j];
      f32x4 p4 = *(const f32x4*)(sprow + j);
      i32x4 m4 = *(const i32x4*)(mrow + j);
      s4.x = (m4.x == 0) ? -1.0e9f : s4.x * p4.x;
      s4.y = (m4.y == 0) ? -1.0e9f : s4.y * p4.y;
      s4.z = (m4.z == 0) ? -1.0e9f : s4.z * p4.z;
      s4.w = (m4.w == 0) ? -1.0e9f : s4.w * p4.w;
      vals[it] = s4;
      mx = fmaxf(mx, fmaxf(fmaxf(s4.x, s4.y), fmaxf(s4.z, s4.w)));
    }
    #pragma unroll
    for (int off = 32; off > 0; off >>= 1)
      mx = fmaxf(mx, __shfl_xor(mx, off));
    float sum = 0.f;
    #pragma unroll
    for (int it = 0; it < 4; ++it) {
      f32x4 e;
      e.x = __expf(vals[it].x - mx);
      e.y = __expf(vals[it].y - mx);
      e.z = __expf(vals[it].z - mx);
      e.w = __expf(vals[it].w - mx);
      vals[it] = e;
      sum += e.x + e.y + e.z + e.w;
    }
    #pragma unroll
    for (int off = 32; off > 0; off >>= 1)
      sum += __shfl_xor(sum, off);
    const float inv = 1.0f / sum;
    #pragma unroll
    for (int it = 0; it < 4; ++it) {
      const int j = lane * 4 + it * 256;
      f32x4 pv = vals[it] * inv;
      *(f32x4*)(prow + j) = pv;                 // coalesced p_attn store
      u16x4 pbv;
      pbv.x = f2bf(pv.x); pbv.y = f2bf(pv.y);
      pbv.z = f2bf(pv.z); pbv.w = f2bf(pv.w);
      *(u16x4*)&pb[r][j] = pbv;
    }
  }

  // ---------- Phase 3: O^T = V^T P^T via MFMA (m=d, n=q, k=attn-k) ----------
  f32x4 oacc = {0.f, 0.f, 0.f, 0.f};
  const float* vbase = vp + bhS * D_DIM;
  for (int vc = 0; vc < 8; ++vc) {             // 8 chunks of 128 k-rows
    __syncthreads();                           // vt reuse + (vc==0) pb ready
    #pragma unroll
    for (int it = 0; it < 8; ++it) {           // stage V chunk transposed
      const int i  = tid + it * 256;           // 2048 f32x4 = 128 rows x 16 col4
      const int rr = i >> 4, c4 = i & 15;      // coalesced 1KB/wave reads
      f32x4 vv = *(const f32x4*)(vbase + (size_t)(vc * 128 + rr) * D_DIM + c4 * 4);
      vt[c4 * 4 + 0][rr] = f2bf(vv.x);
      vt[c4 * 4 + 1][rr] = f2bf(vv.y);
      vt[c4 * 4 + 2][rr] = f2bf(vv.z);
      vt[c4 * 4 + 3][rr] = f2bf(vv.w);
    }
    __syncthreads();
    #pragma unroll
    for (int kk = 0; kk < 4; ++kk) {
      const int kl = kk * 32;
      // A-frag (V^T): lane holds V^T[wave*16+row16][kl+quad*8+j] — contiguous in vt
      short8 af = *(const short8*)&vt[wave * 16 + row16][kl + quad * 8];
      // B-frag (P^T): B[k][n=q] = P[q][k] — contiguous in pb rows
      short8 bf = *(const short8*)&pb[row16][vc * 128 + kl + quad * 8];
      oacc = __builtin_amdgcn_mfma_f32_16x16x32_bf16(af, bf, oacc, 0, 0, 0);
    }
  }

  // C layout of O^T: col = row16 = q, row = quad*4+r = d-local -> 4 contiguous d
  float* orow = outp + (bhS + q0 + row16) * D_DIM + wave * 16 + quad * 4;
  *(f32x4*)orow = oacc;
}

extern "C" void kernel_launch(void* const* d_in, const int* in_sizes, int n_in,
                              void* d_out, int out_size, void* d_ws, size_t ws_size,
                              hipStream_t stream) {
  const float* q    = (const float*)d_in[0];
  const float* k    = (const float*)d_in[1];
  const float* v    = (const float*)d_in[2];
  const float* sph  = (const float*)d_in[3];
  const int*   mask = (const int*)d_in[4];
  float* out  = (float*)d_out;                          // [4,8,1024,64]
  float* patt = out + (size_t)4 * 8 * 1024 * 64;        // [4,8,1024,1024]

  dim3 grid(32 * 64);   // (b*h) * q-tiles
  dim3 block(256);
  hipLaunchKernelGGL(sdpa_kernel, grid, block, 0, stream,
                     q, k, v, sph, mask, out, patt);
}

// Round 2
// 390.874 us; speedup vs baseline: 1.1291x; 1.1291x over previous
//
#include <hip/hip_runtime.h>

#define S_DIM 1024
#define D_DIM 64
#define TQ 16

typedef __attribute__((ext_vector_type(4))) float f32x4;
typedef __attribute__((ext_vector_type(4))) int i32x4;
typedef __attribute__((ext_vector_type(4))) unsigned short u16x4;
typedef __attribute__((ext_vector_type(8))) short short8;

__device__ inline unsigned short f2bf(float x) {
  // round-to-nearest-even fp32 -> bf16
  unsigned int u = __builtin_bit_cast(unsigned int, x);
  u += 0x7fffu + ((u >> 16) & 1u);
  return (unsigned short)(u >> 16);
}

__device__ inline short8 pack8(f32x4 a, f32x4 b) {
  short8 r;
  r[0] = (short)f2bf(a.x); r[1] = (short)f2bf(a.y);
  r[2] = (short)f2bf(a.z); r[3] = (short)f2bf(a.w);
  r[4] = (short)f2bf(b.x); r[5] = (short)f2bf(b.y);
  r[6] = (short)f2bf(b.z); r[7] = (short)f2bf(b.w);
  return r;
}

__global__ __launch_bounds__(256, 3)
void sdpa_kernel(const float* __restrict__ qp, const float* __restrict__ kp,
                 const float* __restrict__ vp, const float* __restrict__ sphp,
                 const int* __restrict__ maskp,
                 float* __restrict__ outp, float* __restrict__ pp)
{
  // LDS budget ~51 KB -> 3 blocks/CU (12 waves/CU) with VGPR <= 170.
  __shared__ unsigned short pb[TQ][1032];   // P (bf16) for PV        33024 B
  __shared__ unsigned short vt[64][136];    // V^T chunk (bf16)       17408 B
  __shared__ float          red[2][4][16];  // cross-wave max/sum       512 B

  const int tid   = threadIdx.x;
  const int lane  = tid & 63;
  const int wave  = tid >> 6;
  const int row16 = lane & 15;   // MFMA: m/n index
  const int quad  = lane >> 4;   // MFMA: k-chunk / C row-quad

  const int bh = blockIdx.x >> 6;        // 32 (b,h) pairs
  const int qt = blockIdx.x & 63;        // 64 q-tiles of 16 rows
  const int b  = bh >> 3;                // H=8
  const int q0 = qt * TQ;

  const size_t bhS = (size_t)bh * S_DIM;

  // ---------- Phase 1: S^T = K (Q/8)^T via MFMA (m=k, n=q) ----------
  // B-frag (Q): lane holds Q[q0+row16][quad*8+j] — 8 contiguous fp32
  const float* qrow = qp + (bhS + q0 + row16) * D_DIM + quad * 8;
  const f32x4 s8 = {0.125f, 0.125f, 0.125f, 0.125f};  // 1/TEMPERATURE
  f32x4 qa = *(const f32x4*)(qrow);
  f32x4 qb = *(const f32x4*)(qrow + 4);
  f32x4 qc = *(const f32x4*)(qrow + 32);
  f32x4 qd = *(const f32x4*)(qrow + 36);
  const short8 bq0 = pack8(qa * s8, qb * s8);
  const short8 bq1 = pack8(qc * s8, qd * s8);

  // wave owns contiguous 256-k span; scores live in 16 f32x4 regs.
  // lane holds (q = q0+row16, k = kbase + t*16 + quad*4 + r)
  const int kbase = wave * 256;
  f32x4 accs[16];
  #pragma unroll
  for (int t = 0; t < 16; ++t) {
    const float* krow = kp + (bhS + kbase + t * 16 + row16) * D_DIM + quad * 8;
    f32x4 ka = *(const f32x4*)(krow);
    f32x4 kb = *(const f32x4*)(krow + 4);
    f32x4 kc = *(const f32x4*)(krow + 32);
    f32x4 kd = *(const f32x4*)(krow + 36);
    f32x4 acc = {0.f, 0.f, 0.f, 0.f};
    acc = __builtin_amdgcn_mfma_f32_16x16x32_bf16(pack8(ka, kb), bq0, acc, 0, 0, 0);
    acc = __builtin_amdgcn_mfma_f32_16x16x32_bf16(pack8(kc, kd), bq1, acc, 0, 0, 0);
    accs[t] = acc;
  }

  // ---------- Phase 2: sph*mask + softmax, all vectorized f32x4 ----------
  const int q = q0 + row16;
  const float* sprow = sphp + (bhS + q) * S_DIM + kbase + quad * 4;
  const int*   mrow  = maskp + ((size_t)b * S_DIM + q) * S_DIM + kbase + quad * 4;

  float mx = -3.0e38f;
  #pragma unroll
  for (int t = 0; t < 16; ++t) {
    f32x4 p4 = *(const f32x4*)(sprow + t * 16);
    i32x4 m4 = *(const i32x4*)(mrow + t * 16);
    f32x4 s  = accs[t];
    s.x = (m4.x == 0) ? -1.0e9f : s.x * p4.x;
    s.y = (m4.y == 0) ? -1.0e9f : s.y * p4.y;
    s.z = (m4.z == 0) ? -1.0e9f : s.z * p4.z;
    s.w = (m4.w == 0) ? -1.0e9f : s.w * p4.w;
    accs[t] = s;
    mx = fmaxf(mx, fmaxf(fmaxf(s.x, s.y), fmaxf(s.z, s.w)));
  }
  // combine the 4 quads (lanes sharing row16): xor 16, 32
  mx = fmaxf(mx, __shfl_xor(mx, 16));
  mx = fmaxf(mx, __shfl_xor(mx, 32));
  if (quad == 0) red[0][wave][row16] = mx;
  __syncthreads();
  mx = fmaxf(fmaxf(red[0][0][row16], red[0][1][row16]),
             fmaxf(red[0][2][row16], red[0][3][row16]));

  float sum = 0.f;
  #pragma unroll
  for (int t = 0; t < 16; ++t) {
    f32x4 e;
    e.x = __expf(accs[t].x - mx);
    e.y = __expf(accs[t].y - mx);
    e.z = __expf(accs[t].z - mx);
    e.w = __expf(accs[t].w - mx);
    accs[t] = e;
    sum += (e.x + e.y) + (e.z + e.w);
  }
  sum += __shfl_xor(sum, 16);
  sum += __shfl_xor(sum, 32);
  if (quad == 0) red[1][wave][row16] = sum;
  __syncthreads();
  sum = (red[1][0][row16] + red[1][1][row16]) + (red[1][2][row16] + red[1][3][row16]);
  const float inv = 1.0f / sum;

  float* prow = pp + (bhS + q) * S_DIM + kbase + quad * 4;
  #pragma unroll
  for (int t = 0; t < 16; ++t) {
    f32x4 pv = accs[t] * inv;
    *(f32x4*)(prow + t * 16) = pv;            // coalesced p_attn store
    u16x4 pbv;
    pbv.x = f2bf(pv.x); pbv.y = f2bf(pv.y);
    pbv.z = f2bf(pv.z); pbv.w = f2bf(pv.w);
    *(u16x4*)&pb[row16][kbase + t * 16 + quad * 4] = pbv;  // 2-way banks: free
  }

  // ---------- Phase 3: O^T = V^T P^T via MFMA (m=d, n=q, k=attn-k) ----------
  f32x4 oacc = {0.f, 0.f, 0.f, 0.f};
  const float* vbase = vp + bhS * D_DIM;
  for (int vc = 0; vc < 8; ++vc) {             // 8 chunks of 128 k-rows
    __syncthreads();                           // vt reuse; (vc==0) pb ready
    #pragma unroll
    for (int it = 0; it < 8; ++it) {           // stage V chunk transposed
      const int i  = it * 256 + tid;           // 2048 f32x4 = 128 rows x 16 col4
      const int c4 = i >> 7, rr = i & 127;     // rr lane-fast -> LDS writes
      f32x4 vv = *(const f32x4*)(vbase + (size_t)(vc * 128 + rr) * D_DIM + c4 * 4);
      vt[c4 * 4 + 0][rr] = f2bf(vv.x);         // consecutive shorts per wave:
      vt[c4 * 4 + 1][rr] = f2bf(vv.y);         // 2 lanes/word = 2-way = free
      vt[c4 * 4 + 2][rr] = f2bf(vv.z);
      vt[c4 * 4 + 3][rr] = f2bf(vv.w);
    }
    __syncthreads();
    #pragma unroll
    for (int kk = 0; kk < 4; ++kk) {
      // A-frag (V^T): lane holds V^T[wave*16+row16][kk*32+quad*8+j]
      short8 af = *(const short8*)&vt[wave * 16 + row16][kk * 32 + quad * 8];
      // B-frag (P^T): B[k][n=q] = P[q][k] — contiguous in pb rows
      short8 bf = *(const short8*)&pb[row16][vc * 128 + kk * 32 + quad * 8];
      oacc = __builtin_amdgcn_mfma_f32_16x16x32_bf16(af, bf, oacc, 0, 0, 0);
    }
  }

  // C layout of O^T: col=row16=q, row=quad*4+r=d-local -> 4 contiguous d
  float* orow = outp + (bhS + q0 + row16) * D_DIM + wave * 16 + quad * 4;
  *(f32x4*)orow = oacc;
}

extern "C" void kernel_launch(void* const* d_in, const int* in_sizes, int n_in,
                              void* d_out, int out_size, void* d_ws, size_t ws_size,
                              hipStream_t stream) {
  const float* q    = (const float*)d_in[0];
  const float* k    = (const float*)d_in[1];
  const float* v    = (const float*)d_in[2];
  const float* sph  = (const float*)d_in[3];
  const int*   mask = (const int*)d_in[4];
  float* out  = (float*)d_out;                          // [4,8,1024,64]
  float* patt = out + (size_t)4 * 8 * 1024 * 64;        // [4,8,1024,1024]

  dim3 grid(32 * 64);   // (b*h) * q-tiles
  dim3 block(256);
  hipLaunchKernelGGL(sdpa_kernel, grid, block, 0, stream,
                     q, k, v, sph, mask, out, patt);
}

// Round 3
// 384.545 us; speedup vs baseline: 1.1477x; 1.0165x over previous
//
#include <hip/hip_runtime.h>

#define S_DIM 1024
#define TQ 16

typedef __attribute__((ext_vector_type(4))) float f32x4;
typedef __attribute__((ext_vector_type(4))) int i32x4;
typedef _Float16 half4 __attribute__((ext_vector_type(4)));
typedef _Float16 half8 __attribute__((ext_vector_type(8)));

__device__ inline half8 pack8h(f32x4 a, f32x4 b) {
  half8 r;
  r[0] = (_Float16)a.x; r[1] = (_Float16)a.y;
  r[2] = (_Float16)a.z; r[3] = (_Float16)a.w;
  r[4] = (_Float16)b.x; r[5] = (_Float16)b.y;
  r[6] = (_Float16)b.z; r[7] = (_Float16)b.w;
  return r;
}

__global__ __launch_bounds__(256, 3)
void sdpa_kernel(const float* __restrict__ qp, const float* __restrict__ kp,
                 const float* __restrict__ vp, const float* __restrict__ sphp,
                 const int* __restrict__ maskp,
                 float* __restrict__ outp, float* __restrict__ pp)
{
  // LDS ~51 KB -> 3 blocks/CU. pb doubles as score-exchange and P (f16) for PV.
  __shared__ _Float16 pb[TQ][1032];   // scores -> exp (f16)       33024 B
  __shared__ _Float16 vt[64][136];    // V^T chunk (f16)           17408 B
  __shared__ float    red[2][4][16];  // cross-wave max/sum          512 B

  const int tid   = threadIdx.x;
  const int lane  = tid & 63;
  const int wave  = tid >> 6;
  const int row16 = lane & 15;   // MFMA: m/n index
  const int quad  = lane >> 4;   // MFMA: k-chunk / C row-quad

  const int bh = blockIdx.x >> 6;        // 32 (b,h) pairs
  const int qt = blockIdx.x & 63;        // 64 q-tiles of 16 rows
  const int b  = bh >> 3;                // H=8
  const int q0 = qt * TQ;

  const size_t bhS = (size_t)bh * S_DIM;

  // ---------- Phase 1: S^T = K (Q/8)^T via MFMA (m=k, n=q); scores -> pb (f16)
  const float* qrow = qp + (bhS + q0 + row16) * 64 + quad * 8;
  const f32x4 s8 = {0.125f, 0.125f, 0.125f, 0.125f};  // 1/TEMPERATURE
  f32x4 qa = *(const f32x4*)(qrow);
  f32x4 qb = *(const f32x4*)(qrow + 4);
  f32x4 qc = *(const f32x4*)(qrow + 32);
  f32x4 qd = *(const f32x4*)(qrow + 36);
  const half8 bq0 = pack8h(qa * s8, qb * s8);
  const half8 bq1 = pack8h(qc * s8, qd * s8);

  const int kbase = wave * 256;          // wave-private 256-k span
  #pragma unroll
  for (int t = 0; t < 16; ++t) {
    const float* krow = kp + (bhS + kbase + t * 16 + row16) * 64 + quad * 8;
    f32x4 ka = *(const f32x4*)(krow);
    f32x4 kb = *(const f32x4*)(krow + 4);
    f32x4 kc = *(const f32x4*)(krow + 32);
    f32x4 kd = *(const f32x4*)(krow + 36);
    f32x4 acc = {0.f, 0.f, 0.f, 0.f};
    acc = __builtin_amdgcn_mfma_f32_16x16x32_f16(pack8h(ka, kb), bq0, acc, 0, 0, 0);
    acc = __builtin_amdgcn_mfma_f32_16x16x32_f16(pack8h(kc, kd), bq1, acc, 0, 0, 0);
    // C: col=row16=q, row=quad*4+r = k-local -> 4 consecutive k for fixed q
    half4 hv; hv[0] = (_Float16)acc.x; hv[1] = (_Float16)acc.y;
    hv[2] = (_Float16)acc.z; hv[3] = (_Float16)acc.w;
    *(half4*)&pb[row16][kbase + t * 16 + quad * 4] = hv;   // 2-way banks: free
  }
  __syncthreads();

  // ---------- Phase 2: softmax in STREAM layout ----------
  // wave w owns k-span [w*256, w*256+256); lane l owns k = l*4..l*4+3.
  // Every sph/mask/p global access = one contiguous 1KB wave transaction.
  const int kcol = kbase + lane * 4;

  // 2b: masked score = s*sph (or -60000), back to pb in place; per-row partial max
  #pragma unroll
  for (int r = 0; r < TQ; ++r) {
    const size_t rowoff = (bhS + q0 + r) * S_DIM + kcol;
    f32x4 p4 = *(const f32x4*)(sphp + rowoff);
    i32x4 m4 = *(const i32x4*)(maskp + (((size_t)b * S_DIM + q0 + r) * S_DIM + kcol));
    half4 sh = *(half4*)&pb[r][kcol];
    f32x4 ms;
    ms.x = (m4.x == 0) ? -60000.f : (float)sh[0] * p4.x;
    ms.y = (m4.y == 0) ? -60000.f : (float)sh[1] * p4.y;
    ms.z = (m4.z == 0) ? -60000.f : (float)sh[2] * p4.z;
    ms.w = (m4.w == 0) ? -60000.f : (float)sh[3] * p4.w;
    half4 hv; hv[0] = (_Float16)ms.x; hv[1] = (_Float16)ms.y;
    hv[2] = (_Float16)ms.z; hv[3] = (_Float16)ms.w;
    *(half4*)&pb[r][kcol] = hv;
    float mx = fmaxf(fmaxf(ms.x, ms.y), fmaxf(ms.z, ms.w));
    #pragma unroll
    for (int off = 32; off > 0; off >>= 1)
      mx = fmaxf(mx, __shfl_xor(mx, off));
    if (lane == 0) red[0][wave][r] = mx;
  }
  __syncthreads();

  // 2c: e = exp(ms - global_max), back to pb (unnormalized); per-row partial sum
  #pragma unroll
  for (int r = 0; r < TQ; ++r) {
    const float mx = fmaxf(fmaxf(red[0][0][r], red[0][1][r]),
                           fmaxf(red[0][2][r], red[0][3][r]));
    half4 sh = *(half4*)&pb[r][kcol];
    f32x4 e;
    e.x = __expf((float)sh[0] - mx);
    e.y = __expf((float)sh[1] - mx);
    e.z = __expf((float)sh[2] - mx);
    e.w = __expf((float)sh[3] - mx);
    half4 hv; hv[0] = (_Float16)e.x; hv[1] = (_Float16)e.y;
    hv[2] = (_Float16)e.z; hv[3] = (_Float16)e.w;
    *(half4*)&pb[r][kcol] = hv;
    float sum = (e.x + e.y) + (e.z + e.w);
    #pragma unroll
    for (int off = 32; off > 0; off >>= 1)
      sum += __shfl_xor(sum, off);
    if (lane == 0) red[1][wave][r] = sum;
  }
  __syncthreads();

  // 2d: p = e * (1/sum) -> coalesced fp32 global store (pb stays unnormalized)
  #pragma unroll
  for (int r = 0; r < TQ; ++r) {
    const float sum = (red[1][0][r] + red[1][1][r]) + (red[1][2][r] + red[1][3][r]);
    const float inv = 1.0f / sum;
    half4 e = *(half4*)&pb[r][kcol];
    f32x4 pv;
    pv.x = (float)e[0] * inv; pv.y = (float)e[1] * inv;
    pv.z = (float)e[2] * inv; pv.w = (float)e[3] * inv;
    *(f32x4*)(pp + (bhS + q0 + r) * S_DIM + kcol) = pv;
  }

  // ---------- Phase 3: O^T = V^T E^T via MFMA; normalize in epilogue ----------
  f32x4 oacc = {0.f, 0.f, 0.f, 0.f};
  const float* vbase = vp + bhS * 64;
  for (int vc = 0; vc < 8; ++vc) {             // 8 chunks of 128 k-rows
    __syncthreads();                           // vt reuse; (vc==0) pb/red ready
    #pragma unroll
    for (int it = 0; it < 8; ++it) {           // stage V chunk transposed
      const int i  = it * 256 + tid;           // 2048 f32x4 = 128 rows x 16 col4
      const int c4 = i >> 7, rr = i & 127;     // rr lane-fast -> LDS 2-way free
      f32x4 vv = *(const f32x4*)(vbase + (size_t)(vc * 128 + rr) * 64 + c4 * 4);
      vt[c4 * 4 + 0][rr] = (_Float16)vv.x;
      vt[c4 * 4 + 1][rr] = (_Float16)vv.y;
      vt[c4 * 4 + 2][rr] = (_Float16)vv.z;
      vt[c4 * 4 + 3][rr] = (_Float16)vv.w;
    }
    __syncthreads();
    #pragma unroll
    for (int kk = 0; kk < 4; ++kk) {
      // A (V^T): lane holds V^T[wave*16+row16][kk*32+quad*8+j]
      half8 af = *(half8*)&vt[wave * 16 + row16][kk * 32 + quad * 8];
      // B (E^T): B[k][n=q] = E[q][k] — contiguous in pb rows
      half8 bf = *(half8*)&pb[row16][vc * 128 + kk * 32 + quad * 8];
      oacc = __builtin_amdgcn_mfma_f32_16x16x32_f16(af, bf, oacc, 0, 0, 0);
    }
  }

  // O^T C-layout: col=row16=q, row=quad*4+r=d-local -> 4 contiguous d.
  // Fold softmax normalization (1/sum of row q) in here.
  const float ssum = (red[1][0][row16] + red[1][1][row16]) +
                     (red[1][2][row16] + red[1][3][row16]);
  const float invq = 1.0f / ssum;
  float* orow = outp + (bhS + q0 + row16) * 64 + wave * 16 + quad * 4;
  *(f32x4*)orow = oacc * invq;
}

extern "C" void kernel_launch(void* const* d_in, const int* in_sizes, int n_in,
                              void* d_out, int out_size, void* d_ws, size_t ws_size,
                              hipStream_t stream) {
  const float* q    = (const float*)d_in[0];
  const float* k    = (const float*)d_in[1];
  const float* v    = (const float*)d_in[2];
  const float* sph  = (const float*)d_in[3];
  const int*   mask = (const int*)d_in[4];
  float* out  = (float*)d_out;                          // [4,8,1024,64]
  float* patt = out + (size_t)4 * 8 * 1024 * 64;        // [4,8,1024,1024]

  dim3 grid(32 * 64);   // (b*h) * q-tiles
  dim3 block(256);
  hipLaunchKernelGGL(sdpa_kernel, grid, block, 0, stream,
                     q, k, v, sph, mask, out, patt);
}